// Round 1
// baseline (1017.253 us; speedup 1.0000x reference)
//
#include <hip/hip_runtime.h>
#include <math.h>

// ArcFace loss, restructured:
//   logits[j] = 64*x[j] for j != t;  logit_t = 64*(x_t*cos(m) - sqrt(1-x_t^2)*sin(m))
//   loss_row  = 64 + log(S') - logit_t,  S' = sum_j exp(64*x_j - 64) - exp(64*x_t-64) + exp(logit_t-64)
// Fixed shift of 64 (|64x|<=64) makes this single-pass: exactly one read of the
// B*C matrix -> memory-bound, roofline ~130us at 6.3 TB/s.

#define MARGIN_COS 0.99500416527802576609556198780387f  // cos(0.1)
#define MARGIN_SIN 0.09983341664682815230681419841062f  // sin(0.1)
#define SCALE 64.0f

__global__ __launch_bounds__(256) void arcface_row_kernel(
    const float* __restrict__ cosine,
    const int* __restrict__ label,
    float* __restrict__ row_loss,
    int C)
{
    const int row = blockIdx.x;
    const float* __restrict__ x = cosine + (size_t)row * (size_t)C;
    const int tid = threadIdx.x;
    const int nthr = blockDim.x;   // 256

    // single pass: sum exp(64*x - 64) over the row, float4-vectorized
    float s = 0.0f;
    const float4* __restrict__ x4 = (const float4*)x;
    const int n4 = C >> 2;
    for (int i = tid; i < n4; i += nthr) {
        float4 v = x4[i];
        s += __expf(SCALE * v.x - SCALE);
        s += __expf(SCALE * v.y - SCALE);
        s += __expf(SCALE * v.z - SCALE);
        s += __expf(SCALE * v.w - SCALE);
    }
    for (int i = (n4 << 2) + tid; i < C; i += nthr) {   // tail (C%4, unused for C=100000)
        s += __expf(SCALE * x[i] - SCALE);
    }

    // wave (64-lane) reduction, then cross-wave via LDS
    #pragma unroll
    for (int off = 32; off > 0; off >>= 1) s += __shfl_down(s, off, 64);
    __shared__ float wsum[4];
    const int wave = tid >> 6;
    if ((tid & 63) == 0) wsum[wave] = s;
    __syncthreads();

    if (tid == 0) {
        float S = wsum[0] + wsum[1] + wsum[2] + wsum[3];
        int t = label[row];
        float loss;
        if (t >= 0 && t < C) {
            float xt = x[t];                       // one extra load; row is L2-warm
            float lt = SCALE * xt;
            float sin_th = sqrtf(fmaxf(0.0f, 1.0f - xt * xt));
            float lmod = SCALE * (xt * MARGIN_COS - sin_th * MARGIN_SIN);
            S = S - __expf(lt - SCALE) + __expf(lmod - SCALE);
            loss = SCALE + __logf(S) - lmod;       // -(lmod - max - lse), shift-invariant
        } else {
            // invalid label (label==-1): no margin; JAX take_along_axis clamps/wraps.
            int tw = (t < 0) ? (t + C) : (C - 1);
            if (tw < 0) tw = 0;
            float lt = SCALE * x[tw];
            loss = SCALE + __logf(S) - lt;
        }
        row_loss[row] = loss;
    }
}

__global__ __launch_bounds__(256) void arcface_reduce_kernel(
    const float* __restrict__ row_loss, float* __restrict__ out, int B)
{
    const int tid = threadIdx.x;
    float s = 0.0f;
    for (int i = tid; i < B; i += 256) s += row_loss[i];
    #pragma unroll
    for (int off = 32; off > 0; off >>= 1) s += __shfl_down(s, off, 64);
    __shared__ float wsum[4];
    const int wave = tid >> 6;
    if ((tid & 63) == 0) wsum[wave] = s;
    __syncthreads();
    if (tid == 0) {
        float S = wsum[0] + wsum[1] + wsum[2] + wsum[3];
        out[0] = S / (float)B;
    }
}

extern "C" void kernel_launch(void* const* d_in, const int* in_sizes, int n_in,
                              void* d_out, int out_size, void* d_ws, size_t ws_size,
                              hipStream_t stream)
{
    const float* cosine = (const float*)d_in[0];
    const int* label = (const int*)d_in[1];
    float* out = (float*)d_out;
    float* row_loss = (float*)d_ws;

    const int B = in_sizes[1];
    const int C = in_sizes[0] / in_sizes[1];

    arcface_row_kernel<<<B, 256, 0, stream>>>(cosine, label, row_loss, C);
    arcface_reduce_kernel<<<1, 256, 0, stream>>>(row_loss, out, B);
}